// Round 12
// baseline (436.729 us; speedup 1.0000x reference)
//
#include <hip/hip_runtime.h>
#include <math.h>

// (B, L, E, H) = (4, 1024, 2048, 16), DH = 128
#define BB 4
#define LL 1024
#define EE 2048
#define HH 16
#define DHD 128
#define NTOK 4096
#define NBH 64
#define OUT0_ELEMS 8388608     // B*L*E

typedef __attribute__((ext_vector_type(8))) short short8;
typedef __attribute__((ext_vector_type(4))) float f32x4;
typedef __attribute__((ext_vector_type(4))) unsigned short ushort4v;
typedef __attribute__((ext_vector_type(8))) unsigned short ushort8v;

__device__ __forceinline__ unsigned short f2bf(float x) {
    union { float f; unsigned int u; } v; v.f = x;
    unsigned int r = v.u + 0x7FFFu + ((v.u >> 16) & 1u);   // RNE
    return (unsigned short)(r >> 16);
}
__device__ __forceinline__ float bf2f(unsigned short h) {
    union { unsigned int u; float f; } v; v.u = ((unsigned int)h) << 16;
    return v.f;
}

__device__ __forceinline__ void gload16(const void* g, void* l) {
    __builtin_amdgcn_global_load_lds((const __attribute__((address_space(1))) void*)g,
                                     (__attribute__((address_space(3))) void*)l,
                                     16, 0, 0);
}

// ---------------------------------------------------------------------------
// One-shot fp32 -> bf16 convert of X and all 4 weights.
// ---------------------------------------------------------------------------
__global__ __launch_bounds__(256)
void cvt_all_k(const float* __restrict__ X, const float* __restrict__ Wq,
               const float* __restrict__ Wk, const float* __restrict__ Wv,
               const float* __restrict__ Wo, unsigned short* __restrict__ Xbf,
               unsigned short* __restrict__ Wqkvb, unsigned short* __restrict__ Wob) {
    size_t g = (size_t)(blockIdx.x * 256 + threadIdx.x) * 8;
    if (g >= 25165824u) return;
    const float* src;
    unsigned short* dst;
    if (g < 8388608u) {
        src = X + g; dst = Xbf + g;
    } else {
        size_t rr = g - 8388608u;
        int wi = (int)(rr >> 22);
        size_t o = rr & 4194303u;
        src = (wi == 0 ? Wq : wi == 1 ? Wk : wi == 2 ? Wv : Wo) + o;
        dst = (wi < 3 ? Wqkvb + ((size_t)wi << 22) : Wob) + o;
    }
    float4 a = *(const float4*)(src);
    float4 b = *(const float4*)(src + 4);
    ushort4v u, w;
    u.x = f2bf(a.x); u.y = f2bf(a.y); u.z = f2bf(a.z); u.w = f2bf(a.w);
    w.x = f2bf(b.x); w.y = f2bf(b.y); w.z = f2bf(b.z); w.w = f2bf(b.w);
    *(ushort4v*)(dst) = u;
    *(ushort4v*)(dst + 4) = w;
}

// ---------------------------------------------------------------------------
// xPos table
// ---------------------------------------------------------------------------
__global__ __launch_bounds__(64) void xpos_table_k(float4* __restrict__ tab) {
    int t = blockIdx.x;
    int j = threadIdx.x;
    float pos = (float)(t - 512);
    float base = (2.0f * (float)j + 51.2f) * (1.0f / 179.2f);
    float sc = powf(base, pos * (1.0f / 512.0f));
    float inv_freq = powf(10000.0f, -(float)j * (1.0f / 64.0f));
    float ang = (float)t * inv_freq;
    float s = sinf(ang);
    float c = cosf(ang);
    tab[(t << 6) | j] = make_float4(c * sc, s * sc, c / sc, s / sc);
}

// ---------------------------------------------------------------------------
// 128x256 8-phase bf16 GEMM (T2+T3+T4+T5), K=2048, BK=64, 8 waves.
// (unchanged from round 11)
// ---------------------------------------------------------------------------
template <int MODE>
__global__ __launch_bounds__(512, 2)
void mm8_k(const unsigned short* __restrict__ Abf, const unsigned short* __restrict__ Bw,
           const float* __restrict__ bq, const float* __restrict__ bk,
           const float* __restrict__ bv, unsigned short* __restrict__ qb,
           unsigned short* __restrict__ kb, unsigned short* __restrict__ vt,
           const float4* __restrict__ tab, float* __restrict__ Cout,
           float scaling) {
    __shared__ alignas(16) char smem[98304];

    const int tid = threadIdx.x;
    const int lane = tid & 63;
    const int wid = tid >> 6;
    const int wr = wid >> 2;
    const int wcn = wid & 3;
    const int fr = lane & 15, fq = lane >> 4;

    const int m0 = blockIdx.y * 128, n0 = blockIdx.x * 256;

    auto stageA = [&](int T) {
        char* dst = smem + ((T & 1) << 14);
        const unsigned short* src = Abf + (size_t)m0 * 2048 + T * 64;
#pragma unroll
        for (int j = 0; j < 2; ++j) {
            int o = (j * 512 + tid) * 16;
            int r = o >> 7;
            int cs = ((o & 127) >> 4) ^ (r & 7);
            gload16(src + (size_t)r * 2048 + cs * 8, dst + o);
        }
    };
    auto stageB = [&](int T, int half) {
        char* dst = smem + 32768 + ((T & 1) << 15) + (half << 14);
        const unsigned short* src = Bw + (size_t)(n0 + half * 128) * 2048 + T * 64;
#pragma unroll
        for (int j = 0; j < 2; ++j) {
            int o = (j * 512 + tid) * 16;
            int r = o >> 7;
            int cs = ((o & 127) >> 4) ^ (r & 7);
            gload16(src + (size_t)r * 2048 + cs * 8, dst + o);
        }
    };
    auto rdA = [&](int buf, int mi, int ks) -> short8 {
        int rl = (wr << 6) + mi * 16 + fr;
        const char* base = smem + (buf << 14);
        return *(const short8*)(base + rl * 128 + ((ks * 4 + fq) ^ (rl & 7)) * 16);
    };
    auto rdB = [&](int buf, int ni, int ks) -> short8 {
        int rb = wcn * 64 + ni * 16 + fr;
        const char* base = smem + 32768 + (buf << 15) + ((rb >> 7) << 14);
        int rh = rb & 127;
        return *(const short8*)(base + rh * 128 + ((ks * 4 + fq) ^ (rh & 7)) * 16);
    };

    f32x4 acc[4][4];
#pragma unroll
    for (int i = 0; i < 4; ++i)
#pragma unroll
        for (int j = 0; j < 4; ++j) acc[i][j] = (f32x4){0.f, 0.f, 0.f, 0.f};

    stageA(0); stageB(0, 0); stageB(0, 1); stageB(1, 0); stageB(1, 1);

    for (int T = 0; T < 32; ++T) {
        const int buf = T & 1;
        if (T < 31) asm volatile("s_waitcnt vmcnt(4)" ::: "memory");
        else        asm volatile("s_waitcnt vmcnt(0)" ::: "memory");
        __builtin_amdgcn_s_barrier();

        short8 a0[2][2], a1[2][2], b0[2][2], b1[2][2];

#pragma unroll
        for (int mi = 0; mi < 2; ++mi) { a0[mi][0] = rdA(buf, mi, 0); a0[mi][1] = rdA(buf, mi, 1); }
#pragma unroll
        for (int ni = 0; ni < 2; ++ni) { b0[ni][0] = rdB(buf, ni, 0); b0[ni][1] = rdB(buf, ni, 1); }
        if (T < 31) stageA(T + 1);
        __builtin_amdgcn_s_barrier();
        __builtin_amdgcn_s_setprio(1);
#pragma unroll
        for (int mi = 0; mi < 2; ++mi)
#pragma unroll
            for (int ni = 0; ni < 2; ++ni) {
                acc[mi][ni] = __builtin_amdgcn_mfma_f32_16x16x32_bf16(a0[mi][0], b0[ni][0], acc[mi][ni], 0, 0, 0);
                acc[mi][ni] = __builtin_amdgcn_mfma_f32_16x16x32_bf16(a0[mi][1], b0[ni][1], acc[mi][ni], 0, 0, 0);
            }
        __builtin_amdgcn_s_setprio(0);
        __builtin_amdgcn_s_barrier();

#pragma unroll
        for (int ni = 0; ni < 2; ++ni) { b1[ni][0] = rdB(buf, ni + 2, 0); b1[ni][1] = rdB(buf, ni + 2, 1); }
        __builtin_amdgcn_s_barrier();
        __builtin_amdgcn_s_setprio(1);
#pragma unroll
        for (int mi = 0; mi < 2; ++mi)
#pragma unroll
            for (int ni = 0; ni < 2; ++ni) {
                acc[mi][ni + 2] = __builtin_amdgcn_mfma_f32_16x16x32_bf16(a0[mi][0], b1[ni][0], acc[mi][ni + 2], 0, 0, 0);
                acc[mi][ni + 2] = __builtin_amdgcn_mfma_f32_16x16x32_bf16(a0[mi][1], b1[ni][1], acc[mi][ni + 2], 0, 0, 0);
            }
        __builtin_amdgcn_s_setprio(0);
        __builtin_amdgcn_s_barrier();

#pragma unroll
        for (int mi = 0; mi < 2; ++mi) { a1[mi][0] = rdA(buf, mi + 2, 0); a1[mi][1] = rdA(buf, mi + 2, 1); }
        if (T < 30) stageB(T + 2, 0);
        __builtin_amdgcn_s_barrier();
        __builtin_amdgcn_s_setprio(1);
#pragma unroll
        for (int mi = 0; mi < 2; ++mi)
#pragma unroll
            for (int ni = 0; ni < 2; ++ni) {
                acc[mi + 2][ni] = __builtin_amdgcn_mfma_f32_16x16x32_bf16(a1[mi][0], b0[ni][0], acc[mi + 2][ni], 0, 0, 0);
                acc[mi + 2][ni] = __builtin_amdgcn_mfma_f32_16x16x32_bf16(a1[mi][1], b0[ni][1], acc[mi + 2][ni], 0, 0, 0);
            }
        __builtin_amdgcn_s_setprio(0);
        __builtin_amdgcn_s_barrier();

        if (T < 30) stageB(T + 2, 1);
        __builtin_amdgcn_s_barrier();
        __builtin_amdgcn_s_setprio(1);
#pragma unroll
        for (int mi = 0; mi < 2; ++mi)
#pragma unroll
            for (int ni = 0; ni < 2; ++ni) {
                acc[mi + 2][ni + 2] = __builtin_amdgcn_mfma_f32_16x16x32_bf16(a1[mi][0], b1[ni][0], acc[mi + 2][ni + 2], 0, 0, 0);
                acc[mi + 2][ni + 2] = __builtin_amdgcn_mfma_f32_16x16x32_bf16(a1[mi][1], b1[ni][1], acc[mi + 2][ni + 2], 0, 0, 0);
            }
        __builtin_amdgcn_s_setprio(0);
        __builtin_amdgcn_s_barrier();
    }

    if constexpr (MODE == 1) {
        const float* bias = bq;
#pragma unroll
        for (int mi = 0; mi < 4; ++mi)
#pragma unroll
            for (int ni = 0; ni < 4; ++ni)
#pragma unroll
                for (int rg = 0; rg < 4; ++rg) {
                    int m = m0 + wr * 64 + mi * 16 + fq * 4 + rg;
                    int n = n0 + wcn * 64 + ni * 16 + fr;
                    Cout[(size_t)m * EE + n] = acc[mi][ni][rg] + bias[n];
                }
        return;
    } else {
        const int w = n0 >> 11;
        const float* bsel = (w == 0) ? bq : (w == 1) ? bk : bv;
        const float alpha = (w == 0) ? scaling : 1.0f;
        const int hbase = (n0 & 2047) >> 7;
        const int b_ = m0 >> 10;
        const int m0r = m0 & 1023;
        float* slab = (float*)smem;

        unsigned short* qk = (w == 0) ? qb : kb;
        __syncthreads();
#pragma unroll
        for (int sl = 0; sl < 4; ++sl) {
            if (wr == (sl >> 1)) {
#pragma unroll
                for (int mi2 = 0; mi2 < 2; ++mi2) {
                    int mi = ((sl & 1) << 1) + mi2;
#pragma unroll
                    for (int ni = 0; ni < 4; ++ni) {
                        int scol = wcn * 64 + ni * 16 + fr;
                        float bias = bsel[(n0 & 2047) + scol];
#pragma unroll
                        for (int rg = 0; rg < 4; ++rg) {
                            int srow = (mi2 << 4) + fq * 4 + rg;
                            slab[srow * 260 + scol] = alpha * (acc[mi][ni][rg] + bias);
                        }
                    }
                }
            }
            __syncthreads();

            if (w < 2) {
                int sr = tid >> 4, cg = tid & 15;
                int t = m0r + (sl << 5) + sr;
                int h = hbase + (cg >> 3);
                int d0 = (cg & 7) << 4;
                const float* SR = slab + sr * 260 + cg * 16;
                ushort8v h0, h1;
#pragma unroll
                for (int p = 0; p < 4; ++p) {
                    float x = SR[2 * p], y = SR[2 * p + 1];
                    float4 tb = tab[(t << 6) | ((d0 >> 1) + p)];
                    float c = (w == 0) ? tb.x : tb.z;
                    float s = (w == 0) ? tb.y : tb.w;
                    h0[2 * p]     = f2bf(x * c - y * s);
                    h0[2 * p + 1] = f2bf(y * c + x * s);
                }
#pragma unroll
                for (int p = 0; p < 4; ++p) {
                    float x = SR[8 + 2 * p], y = SR[8 + 2 * p + 1];
                    float4 tb = tab[(t << 6) | ((d0 >> 1) + 4 + p)];
                    float c = (w == 0) ? tb.x : tb.z;
                    float s = (w == 0) ? tb.y : tb.w;
                    h1[2 * p]     = f2bf(x * c - y * s);
                    h1[2 * p + 1] = f2bf(y * c + x * s);
                }
                unsigned short* DR = qk + (((size_t)(b_ * HH + h)) << 17) + ((size_t)t << 7) + d0;
                *(ushort8v*)(DR) = h0;
                *(ushort8v*)(DR + 8) = h1;
            } else {
                int vcol = tid >> 1, th = tid & 1;
                int h = hbase + (vcol >> 7), d = vcol & 127;
                ushort8v h0, h1;
#pragma unroll
                for (int p = 0; p < 8; ++p)
                    h0[p] = f2bf(slab[(th * 16 + p) * 260 + vcol]);
#pragma unroll
                for (int p = 0; p < 8; ++p)
                    h1[p] = f2bf(slab[(th * 16 + 8 + p) * 260 + vcol]);
                unsigned short* DR = vt + (((size_t)((b_ * HH + h) * 128 + d)) << 10)
                                     + m0r + (sl << 5) + th * 16;
                *(ushort8v*)(DR) = h0;
                *(ushort8v*)(DR + 8) = h1;
            }
            __syncthreads();
        }
    }
}

// ---------------------------------------------------------------------------
// scores_k: one block per causal 128x128 tile. K-loop now double-buffered
// with counted vmcnt(4) (2-phase T3-min): stage(ks+1) in flight during MFMA.
// LDS 32KB: lA[2] @0 (2x8KB), lB[2] @16KB (2x8KB); epilogue slab aliases @0.
// ---------------------------------------------------------------------------
__global__ __launch_bounds__(256)
void scores_k(const unsigned short* __restrict__ qb, const unsigned short* __restrict__ kb,
              const float* __restrict__ rel, unsigned short* __restrict__ ebuf,
              float* __restrict__ psum) {
    __shared__ alignas(16) char smem[32768];
    float* slab = (float*)smem;

    const int tid = threadIdx.x;
    const int lane = tid & 63, wave = tid >> 6;
    const int wr = wave >> 1, wc = wave & 1;
    const int fr = lane & 15, fq = lane >> 4;

    const int flat = blockIdx.y * 36 + blockIdx.x;
    const int xcd = flat & 7, rmp = flat >> 3;
    int idx = rmp % 36;
    const int bh = (rmp / 36) * 8 + xcd;

    int tt = (int)((sqrtf(8.f * (float)idx + 1.f) - 1.f) * 0.5f);
    while ((tt + 1) * (tt + 2) / 2 <= idx) ++tt;
    while (tt * (tt + 1) / 2 > idx) --tt;
    const int ss = idx - tt * (tt + 1) / 2;
    const int t0 = tt << 7, s0 = ss << 7;

    const unsigned short* Q = qb + ((size_t)bh << 17);
    const unsigned short* K = kb + ((size_t)bh << 17);

    auto stage = [&](int ks) {
        int b = ks & 1;
        int k0 = ks << 5;
        unsigned short* A = (unsigned short*)(smem + b * 8192);
        unsigned short* Bm = (unsigned short*)(smem + 16384 + b * 8192);
#pragma unroll
        for (int i = 0; i < 2; ++i) {
            int c = i * 256 + tid;
            int r = c >> 2, kc = c & 3;
            gload16(Q + (size_t)(t0 + r) * 128 + k0 + kc * 8, &A[c * 8]);
        }
#pragma unroll
        for (int i = 0; i < 2; ++i) {
            int c = i * 256 + tid;
            int r = c >> 2, kc = c & 3;
            gload16(K + (size_t)(s0 + r) * 128 + k0 + kc * 8, &Bm[c * 8]);
        }
    };

    f32x4 acc[4][4];
#pragma unroll
    for (int i = 0; i < 4; ++i)
#pragma unroll
        for (int j = 0; j < 4; ++j) acc[i][j] = (f32x4){0.f, 0.f, 0.f, 0.f};

    stage(0);
    for (int ks = 0; ks < 4; ++ks) {
        if (ks < 3) { stage(ks + 1); asm volatile("s_waitcnt vmcnt(4)" ::: "memory"); }
        else        { asm volatile("s_waitcnt vmcnt(0)" ::: "memory"); }
        __builtin_amdgcn_s_barrier();

        const unsigned short* A = (const unsigned short*)(smem + (ks & 1) * 8192);
        const unsigned short* Bm = (const unsigned short*)(smem + 16384 + (ks & 1) * 8192);
        short8 afr[4], bfr[4];
#pragma unroll
        for (int mi = 0; mi < 4; ++mi)
            afr[mi] = *(const short8*)&A[(wr * 64 + mi * 16 + fr) * 32 + fq * 8];
#pragma unroll
        for (int ni = 0; ni < 4; ++ni)
            bfr[ni] = *(const short8*)&Bm[(wc * 64 + ni * 16 + fr) * 32 + fq * 8];
#pragma unroll
        for (int mi = 0; mi < 4; ++mi)
#pragma unroll
            for (int ni = 0; ni < 4; ++ni)
                acc[mi][ni] = __builtin_amdgcn_mfma_f32_16x16x32_bf16(
                    afr[mi], bfr[ni], acc[mi][ni], 0, 0, 0);
        __builtin_amdgcn_s_barrier();
    }

    unsigned short* EO = ebuf + ((size_t)bh << 20);
    const float* RLb = rel + ((size_t)bh << 20);
#pragma unroll
    for (int sl = 0; sl < 4; ++sl) {
        if (wr == (sl >> 1)) {
#pragma unroll
            for (int mi2 = 0; mi2 < 2; ++mi2) {
                int mi = ((sl & 1) << 1) + mi2;
#pragma unroll
                for (int ni = 0; ni < 4; ++ni)
#pragma unroll
                    for (int r = 0; r < 4; ++r) {
                        int srow = (mi2 << 4) + (fq << 2) + r;
                        int col = (wc << 6) + (ni << 4) + fr;
                        slab[srow * 128 + (col ^ (((srow >> 2) & 3) << 4))] = acc[mi][ni][r];
                    }
            }
        }
        __syncthreads();
        {
            int srow = tid >> 3;
            int tg = t0 + (sl << 5) + srow;
            const float* RL = RLb + ((size_t)tg << 10) + s0;
            unsigned short* ER = EO + ((size_t)tg << 10) + s0;
            float rsum = 0.f;
#pragma unroll
            for (int c = 0; c < 4; ++c) {
                int col = ((tid & 7) << 2) + (c << 5);
                float4 sv = *(const float4*)&slab[srow * 128 + (col ^ (((srow >> 2) & 3) << 4))];
                float4 rl = *(const float4*)(RL + col);
                float4 e;
                e.x = (s0 + col     <= tg) ? __expf(sv.x + rl.x - 15.f) : 0.f;
                e.y = (s0 + col + 1 <= tg) ? __expf(sv.y + rl.y - 15.f) : 0.f;
                e.z = (s0 + col + 2 <= tg) ? __expf(sv.z + rl.z - 15.f) : 0.f;
                e.w = (s0 + col + 3 <= tg) ? __expf(sv.w + rl.w - 15.f) : 0.f;
                ushort4v h;
                h.x = f2bf(e.x); h.y = f2bf(e.y); h.z = f2bf(e.z); h.w = f2bf(e.w);
                *(ushort4v*)(ER + col) = h;
                rsum += e.x + e.y + e.z + e.w;
            }
            rsum += __shfl_xor(rsum, 1);
            rsum += __shfl_xor(rsum, 2);
            rsum += __shfl_xor(rsum, 4);
            if ((tid & 7) == 0)
                psum[((((size_t)bh << 10) + tg) << 3) + ss] = rsum;
        }
        __syncthreads();
    }
}

// ---------------------------------------------------------------------------
// pvw_k: per (bh, 64-row t-strip), double-buffered s-tiles with counted
// vmcnt(6) (2-phase T3-min). LDS 48.3KB -> 3 blocks/CU. Per tile: P-write
// (final normalized, float4) + PV MFMA; stage(j+1) DMA in flight throughout.
// ---------------------------------------------------------------------------
__global__ __launch_bounds__(256)
void pvw_k(const unsigned short* __restrict__ ebuf, const unsigned short* __restrict__ vt,
           const float* __restrict__ psum, float* __restrict__ attnP,
           unsigned short* __restrict__ am) {
    __shared__ alignas(16) unsigned short lE[2][64 * 64];
    __shared__ alignas(16) unsigned short lV[2][128 * 64];
    __shared__ float lInvF[64];

    const int tid = threadIdx.x;
    const int lane = tid & 63, wave = tid >> 6;
    const int wr = wave >> 1, wc = wave & 1;
    const int fr = lane & 15, fq = lane >> 4;
    const int strip = 15 - blockIdx.y;        // heavy first
    const int t0 = strip << 6;
    const int bh = blockIdx.x;
    const int hh = bh & 15, bb = bh >> 4;
    const int n_s = strip + 1;

    const unsigned short* EB = ebuf + ((size_t)bh << 20) + ((size_t)t0 << 10);
    const unsigned short* Vb = vt + ((size_t)bh << 17);
    float* PO = attnP + (((size_t)(hh * BB + bb)) << 20) + ((size_t)t0 << 10);

    if (tid < 64) {
        const float* p = psum + ((((size_t)bh << 10) + t0 + tid) << 3);
        const int tt = t0 >> 7;
        float s = 0.f;
#pragma unroll
        for (int j = 0; j < 8; ++j) s += (j <= tt) ? p[j] : 0.f;
        lInvF[tid] = 1.f / s;
    }
    __syncthreads();                           // lInvF visible; no stages yet

    auto stage = [&](int j) {
        int b = j & 1;
        int s0 = j << 6;
#pragma unroll
        for (int i = 0; i < 2; ++i) {
            int o = (i * 256 + tid) * 16;
            int r = o >> 7;
            int cb = (o & 127) ^ ((r & 7) << 4);
            gload16(EB + (size_t)r * 1024 + s0 + (cb >> 1), (char*)lE[b] + o);
        }
#pragma unroll
        for (int i = 0; i < 4; ++i) {
            int o = (i * 256 + tid) * 16;
            int r = o >> 7;
            int cb = (o & 127) ^ ((r & 7) << 4);
            gload16(Vb + (size_t)r * 1024 + s0 + (cb >> 1), (char*)lV[b] + o);
        }
    };

    f32x4 acc[2][4];
#pragma unroll
    for (int i = 0; i < 2; ++i)
#pragma unroll
        for (int j = 0; j < 4; ++j) acc[i][j] = (f32x4){0.f, 0.f, 0.f, 0.f};

    stage(0);
    for (int j = 0; j < n_s; ++j) {
        const int b = j & 1;
        if (j + 1 < n_s) { stage(j + 1); asm volatile("s_waitcnt vmcnt(6)" ::: "memory"); }
        else             { asm volatile("s_waitcnt vmcnt(0)" ::: "memory"); }
        __builtin_amdgcn_s_barrier();
        const int s0 = j << 6;

        // P write: p = e * inv, float4 coalesced (16 cols per thread)
        {
            int row = tid >> 2, col0 = (tid & 3) << 4;
            float inv = lInvF[row];
            float* PR = PO + (size_t)row * 1024 + s0 + col0;
#pragma unroll
            for (int cc = 0; cc < 2; ++cc) {
                int cbyte = ((col0 + cc * 8) * 2) ^ ((row & 7) << 4);
                ushort8v ev = *(const ushort8v*)((const char*)lE[b] + row * 128 + cbyte);
                float4 p0, p1;
                p0.x = bf2f(ev[0]) * inv; p0.y = bf2f(ev[1]) * inv;
                p0.z = bf2f(ev[2]) * inv; p0.w = bf2f(ev[3]) * inv;
                p1.x = bf2f(ev[4]) * inv; p1.y = bf2f(ev[5]) * inv;
                p1.z = bf2f(ev[6]) * inv; p1.w = bf2f(ev[7]) * inv;
                *(float4*)(PR + cc * 8) = p0;
                *(float4*)(PR + cc * 8 + 4) = p1;
            }
        }

        // PV MFMA: O[64t x 128d] += e @ V^T^T, K = 64
#pragma unroll
        for (int ks = 0; ks < 2; ++ks) {
            short8 pf[2], vf[4];
#pragma unroll
            for (int mi = 0; mi < 2; ++mi) {
                int row = wr * 32 + mi * 16 + fr;
                int cb = (ks * 64 + fq * 16) ^ ((row & 7) << 4);
                pf[mi] = *(const short8*)((const char*)lE[b] + row * 128 + cb);
            }
#pragma unroll
            for (int ni = 0; ni < 4; ++ni) {
                int row = wc * 64 + ni * 16 + fr;
                int cb = (ks * 64 + fq * 16) ^ ((row & 7) << 4);
                vf[ni] = *(const short8*)((const char*)lV[b] + row * 128 + cb);
            }
#pragma unroll
            for (int mi = 0; mi < 2; ++mi)
#pragma unroll
                for (int ni = 0; ni < 4; ++ni)
                    acc[mi][ni] = __builtin_amdgcn_mfma_f32_16x16x32_bf16(
                        pf[mi], vf[ni], acc[mi][ni], 0, 0, 0);
        }
        __builtin_amdgcn_s_barrier();
    }

    // zero-fill cols [t0+64, 1024)
    {
        int row = tid >> 2;
        float4 z = make_float4(0.f, 0.f, 0.f, 0.f);
        for (int c = (n_s << 6) + ((tid & 3) << 2); c < 1024; c += 16)
            *(float4*)(PO + (size_t)row * 1024 + c) = z;
    }

    // O epilogue: scale by 1/l, write am (B,L,E) bf16
#pragma unroll
    for (int mi = 0; mi < 2; ++mi)
#pragma unroll
        for (int ni = 0; ni < 4; ++ni)
#pragma unroll
            for (int r = 0; r < 4; ++r) {
                int tl = wr * 32 + mi * 16 + fq * 4 + r;
                int d = wc * 64 + ni * 16 + fr;
                float o = acc[mi][ni][r] * lInvF[tl];
                am[(((size_t)(bb * 1024 + t0 + tl)) << 11) + hh * 128 + d] = f2bf(o);
            }
}

// ---------------------------------------------------------------------------
extern "C" void kernel_launch(void* const* d_in, const int* in_sizes, int n_in,
                              void* d_out, int out_size, void* d_ws, size_t ws_size,
                              hipStream_t stream) {
    const float* query = (const float*)d_in[0];
    const float* Wq    = (const float*)d_in[1];
    const float* bq    = (const float*)d_in[2];
    const float* Wk    = (const float*)d_in[3];
    const float* bk    = (const float*)d_in[4];
    const float* Wv    = (const float*)d_in[5];
    const float* bv    = (const float*)d_in[6];
    const float* Wo    = (const float*)d_in[7];
    const float* bo    = (const float*)d_in[8];
    const float* rel   = (const float*)d_in[10];

    float* out    = (float*)d_out;              // (B, L, E)
    float* attn_w = out + OUT0_ELEMS;           // (H, B, L, L)

    char* w = (char*)d_ws;
    unsigned short* Xbf   = (unsigned short*)(w);               // 16MB
    unsigned short* Wqkvb = (unsigned short*)(w + (16 << 20));  // 24MB
    unsigned short* Wob   = (unsigned short*)(w + (40 << 20));  // 8MB
    unsigned short* qb    = (unsigned short*)(w + (48 << 20));  // 16MB (BH,L,DH)
    unsigned short* kb    = (unsigned short*)(w + (64 << 20));  // 16MB
    unsigned short* vt    = (unsigned short*)(w + (80 << 20));  // 16MB (BH,DH,L)
    unsigned short* am    = (unsigned short*)(w + (96 << 20));  // 16MB (B,L,E)
    float4* tab           = (float4*)(w + (112 << 20));         // 1MB
    float* psum           = (float*)(w + (113u << 20));         // 2MB
    unsigned short* ebuf  = (unsigned short*)(w + (128u << 20)); // 128MB

    const float scaling = 0.08838834764831845f; // DH^-0.5

    xpos_table_k<<<LL, 64, 0, stream>>>(tab);

    cvt_all_k<<<12288, 256, 0, stream>>>(query, Wq, Wk, Wv, Wo, Xbf, Wqkvb, Wob);

    dim3 gqkv(24, 32);                           // 128x256 tiles, 768 blocks
    mm8_k<0><<<gqkv, 512, 0, stream>>>(Xbf, Wqkvb, bq, bk, bv, qb, kb, vt, tab,
                                       nullptr, scaling);

    dim3 gsc(36, NBH);
    scores_k<<<gsc, 256, 0, stream>>>(qb, kb, rel, ebuf, psum);

    dim3 gpv(NBH, 16);
    pvw_k<<<gpv, 256, 0, stream>>>(ebuf, vt, psum, attn_w, am);

    dim3 gout(8, 32);                            // 128x256 tiles, 256 blocks
    mm8_k<1><<<gout, 512, 0, stream>>>(am, Wob, bo, nullptr, nullptr, nullptr,
                                       nullptr, nullptr, tab, out, 1.0f);
}

// Round 13
// 420.264 us; speedup vs baseline: 1.0392x; 1.0392x over previous
//
#include <hip/hip_runtime.h>
#include <math.h>

// (B, L, E, H) = (4, 1024, 2048, 16), DH = 128
#define BB 4
#define LL 1024
#define EE 2048
#define HH 16
#define DHD 128
#define NTOK 4096
#define NBH 64
#define OUT0_ELEMS 8388608     // B*L*E

typedef __attribute__((ext_vector_type(8))) short short8;
typedef __attribute__((ext_vector_type(4))) float f32x4;
typedef __attribute__((ext_vector_type(4))) unsigned short ushort4v;
typedef __attribute__((ext_vector_type(8))) unsigned short ushort8v;

__device__ __forceinline__ unsigned short f2bf(float x) {
    union { float f; unsigned int u; } v; v.f = x;
    unsigned int r = v.u + 0x7FFFu + ((v.u >> 16) & 1u);   // RNE
    return (unsigned short)(r >> 16);
}
__device__ __forceinline__ float bf2f(unsigned short h) {
    union { unsigned int u; float f; } v; v.u = ((unsigned int)h) << 16;
    return v.f;
}

__device__ __forceinline__ void gload16(const void* g, void* l) {
    __builtin_amdgcn_global_load_lds((const __attribute__((address_space(1))) void*)g,
                                     (__attribute__((address_space(3))) void*)l,
                                     16, 0, 0);
}

// ---------------------------------------------------------------------------
// One-shot fp32 -> bf16 convert of X and all 4 weights.
// ---------------------------------------------------------------------------
__global__ __launch_bounds__(256)
void cvt_all_k(const float* __restrict__ X, const float* __restrict__ Wq,
               const float* __restrict__ Wk, const float* __restrict__ Wv,
               const float* __restrict__ Wo, unsigned short* __restrict__ Xbf,
               unsigned short* __restrict__ Wqkvb, unsigned short* __restrict__ Wob) {
    size_t g = (size_t)(blockIdx.x * 256 + threadIdx.x) * 8;
    if (g >= 25165824u) return;
    const float* src;
    unsigned short* dst;
    if (g < 8388608u) {
        src = X + g; dst = Xbf + g;
    } else {
        size_t rr = g - 8388608u;
        int wi = (int)(rr >> 22);
        size_t o = rr & 4194303u;
        src = (wi == 0 ? Wq : wi == 1 ? Wk : wi == 2 ? Wv : Wo) + o;
        dst = (wi < 3 ? Wqkvb + ((size_t)wi << 22) : Wob) + o;
    }
    float4 a = *(const float4*)(src);
    float4 b = *(const float4*)(src + 4);
    ushort4v u, w;
    u.x = f2bf(a.x); u.y = f2bf(a.y); u.z = f2bf(a.z); u.w = f2bf(a.w);
    w.x = f2bf(b.x); w.y = f2bf(b.y); w.z = f2bf(b.z); w.w = f2bf(b.w);
    *(ushort4v*)(dst) = u;
    *(ushort4v*)(dst + 4) = w;
}

// ---------------------------------------------------------------------------
// xPos table
// ---------------------------------------------------------------------------
__global__ __launch_bounds__(64) void xpos_table_k(float4* __restrict__ tab) {
    int t = blockIdx.x;
    int j = threadIdx.x;
    float pos = (float)(t - 512);
    float base = (2.0f * (float)j + 51.2f) * (1.0f / 179.2f);
    float sc = powf(base, pos * (1.0f / 512.0f));
    float inv_freq = powf(10000.0f, -(float)j * (1.0f / 64.0f));
    float ang = (float)t * inv_freq;
    float s = sinf(ang);
    float c = cosf(ang);
    tab[(t << 6) | j] = make_float4(c * sc, s * sc, c / sc, s / sc);
}

// ---------------------------------------------------------------------------
// 128x256 8-phase bf16 GEMM (T2+T3+T4+T5), K=2048, BK=64, 8 waves.
// (unchanged from round 11)
// ---------------------------------------------------------------------------
template <int MODE>
__global__ __launch_bounds__(512, 2)
void mm8_k(const unsigned short* __restrict__ Abf, const unsigned short* __restrict__ Bw,
           const float* __restrict__ bq, const float* __restrict__ bk,
           const float* __restrict__ bv, unsigned short* __restrict__ qb,
           unsigned short* __restrict__ kb, unsigned short* __restrict__ vt,
           const float4* __restrict__ tab, float* __restrict__ Cout,
           float scaling) {
    __shared__ alignas(16) char smem[98304];

    const int tid = threadIdx.x;
    const int lane = tid & 63;
    const int wid = tid >> 6;
    const int wr = wid >> 2;
    const int wcn = wid & 3;
    const int fr = lane & 15, fq = lane >> 4;

    const int m0 = blockIdx.y * 128, n0 = blockIdx.x * 256;

    auto stageA = [&](int T) {
        char* dst = smem + ((T & 1) << 14);
        const unsigned short* src = Abf + (size_t)m0 * 2048 + T * 64;
#pragma unroll
        for (int j = 0; j < 2; ++j) {
            int o = (j * 512 + tid) * 16;
            int r = o >> 7;
            int cs = ((o & 127) >> 4) ^ (r & 7);
            gload16(src + (size_t)r * 2048 + cs * 8, dst + o);
        }
    };
    auto stageB = [&](int T, int half) {
        char* dst = smem + 32768 + ((T & 1) << 15) + (half << 14);
        const unsigned short* src = Bw + (size_t)(n0 + half * 128) * 2048 + T * 64;
#pragma unroll
        for (int j = 0; j < 2; ++j) {
            int o = (j * 512 + tid) * 16;
            int r = o >> 7;
            int cs = ((o & 127) >> 4) ^ (r & 7);
            gload16(src + (size_t)r * 2048 + cs * 8, dst + o);
        }
    };
    auto rdA = [&](int buf, int mi, int ks) -> short8 {
        int rl = (wr << 6) + mi * 16 + fr;
        const char* base = smem + (buf << 14);
        return *(const short8*)(base + rl * 128 + ((ks * 4 + fq) ^ (rl & 7)) * 16);
    };
    auto rdB = [&](int buf, int ni, int ks) -> short8 {
        int rb = wcn * 64 + ni * 16 + fr;
        const char* base = smem + 32768 + (buf << 15) + ((rb >> 7) << 14);
        int rh = rb & 127;
        return *(const short8*)(base + rh * 128 + ((ks * 4 + fq) ^ (rh & 7)) * 16);
    };

    f32x4 acc[4][4];
#pragma unroll
    for (int i = 0; i < 4; ++i)
#pragma unroll
        for (int j = 0; j < 4; ++j) acc[i][j] = (f32x4){0.f, 0.f, 0.f, 0.f};

    stageA(0); stageB(0, 0); stageB(0, 1); stageB(1, 0); stageB(1, 1);

    for (int T = 0; T < 32; ++T) {
        const int buf = T & 1;
        if (T < 31) asm volatile("s_waitcnt vmcnt(4)" ::: "memory");
        else        asm volatile("s_waitcnt vmcnt(0)" ::: "memory");
        __builtin_amdgcn_s_barrier();

        short8 a0[2][2], a1[2][2], b0[2][2], b1[2][2];

#pragma unroll
        for (int mi = 0; mi < 2; ++mi) { a0[mi][0] = rdA(buf, mi, 0); a0[mi][1] = rdA(buf, mi, 1); }
#pragma unroll
        for (int ni = 0; ni < 2; ++ni) { b0[ni][0] = rdB(buf, ni, 0); b0[ni][1] = rdB(buf, ni, 1); }
        if (T < 31) stageA(T + 1);
        __builtin_amdgcn_s_barrier();
        __builtin_amdgcn_s_setprio(1);
#pragma unroll
        for (int mi = 0; mi < 2; ++mi)
#pragma unroll
            for (int ni = 0; ni < 2; ++ni) {
                acc[mi][ni] = __builtin_amdgcn_mfma_f32_16x16x32_bf16(a0[mi][0], b0[ni][0], acc[mi][ni], 0, 0, 0);
                acc[mi][ni] = __builtin_amdgcn_mfma_f32_16x16x32_bf16(a0[mi][1], b0[ni][1], acc[mi][ni], 0, 0, 0);
            }
        __builtin_amdgcn_s_setprio(0);
        __builtin_amdgcn_s_barrier();

#pragma unroll
        for (int ni = 0; ni < 2; ++ni) { b1[ni][0] = rdB(buf, ni + 2, 0); b1[ni][1] = rdB(buf, ni + 2, 1); }
        __builtin_amdgcn_s_barrier();
        __builtin_amdgcn_s_setprio(1);
#pragma unroll
        for (int mi = 0; mi < 2; ++mi)
#pragma unroll
            for (int ni = 0; ni < 2; ++ni) {
                acc[mi][ni + 2] = __builtin_amdgcn_mfma_f32_16x16x32_bf16(a0[mi][0], b1[ni][0], acc[mi][ni + 2], 0, 0, 0);
                acc[mi][ni + 2] = __builtin_amdgcn_mfma_f32_16x16x32_bf16(a0[mi][1], b1[ni][1], acc[mi][ni + 2], 0, 0, 0);
            }
        __builtin_amdgcn_s_setprio(0);
        __builtin_amdgcn_s_barrier();

#pragma unroll
        for (int mi = 0; mi < 2; ++mi) { a1[mi][0] = rdA(buf, mi + 2, 0); a1[mi][1] = rdA(buf, mi + 2, 1); }
        if (T < 30) stageB(T + 2, 0);
        __builtin_amdgcn_s_barrier();
        __builtin_amdgcn_s_setprio(1);
#pragma unroll
        for (int mi = 0; mi < 2; ++mi)
#pragma unroll
            for (int ni = 0; ni < 2; ++ni) {
                acc[mi + 2][ni] = __builtin_amdgcn_mfma_f32_16x16x32_bf16(a1[mi][0], b0[ni][0], acc[mi + 2][ni], 0, 0, 0);
                acc[mi + 2][ni] = __builtin_amdgcn_mfma_f32_16x16x32_bf16(a1[mi][1], b0[ni][1], acc[mi + 2][ni], 0, 0, 0);
            }
        __builtin_amdgcn_s_setprio(0);
        __builtin_amdgcn_s_barrier();

        if (T < 30) stageB(T + 2, 1);
        __builtin_amdgcn_s_barrier();
        __builtin_amdgcn_s_setprio(1);
#pragma unroll
        for (int mi = 0; mi < 2; ++mi)
#pragma unroll
            for (int ni = 0; ni < 2; ++ni) {
                acc[mi + 2][ni + 2] = __builtin_amdgcn_mfma_f32_16x16x32_bf16(a1[mi][0], b1[ni][0], acc[mi + 2][ni + 2], 0, 0, 0);
                acc[mi + 2][ni + 2] = __builtin_amdgcn_mfma_f32_16x16x32_bf16(a1[mi][1], b1[ni][1], acc[mi + 2][ni + 2], 0, 0, 0);
            }
        __builtin_amdgcn_s_setprio(0);
        __builtin_amdgcn_s_barrier();
    }

    if constexpr (MODE == 1) {
        const float* bias = bq;
#pragma unroll
        for (int mi = 0; mi < 4; ++mi)
#pragma unroll
            for (int ni = 0; ni < 4; ++ni)
#pragma unroll
                for (int rg = 0; rg < 4; ++rg) {
                    int m = m0 + wr * 64 + mi * 16 + fq * 4 + rg;
                    int n = n0 + wcn * 64 + ni * 16 + fr;
                    Cout[(size_t)m * EE + n] = acc[mi][ni][rg] + bias[n];
                }
        return;
    } else {
        const int w = n0 >> 11;
        const float* bsel = (w == 0) ? bq : (w == 1) ? bk : bv;
        const float alpha = (w == 0) ? scaling : 1.0f;
        const int hbase = (n0 & 2047) >> 7;
        const int b_ = m0 >> 10;
        const int m0r = m0 & 1023;
        float* slab = (float*)smem;

        unsigned short* qk = (w == 0) ? qb : kb;
        __syncthreads();
#pragma unroll
        for (int sl = 0; sl < 4; ++sl) {
            if (wr == (sl >> 1)) {
#pragma unroll
                for (int mi2 = 0; mi2 < 2; ++mi2) {
                    int mi = ((sl & 1) << 1) + mi2;
#pragma unroll
                    for (int ni = 0; ni < 4; ++ni) {
                        int scol = wcn * 64 + ni * 16 + fr;
                        float bias = bsel[(n0 & 2047) + scol];
#pragma unroll
                        for (int rg = 0; rg < 4; ++rg) {
                            int srow = (mi2 << 4) + fq * 4 + rg;
                            slab[srow * 260 + scol] = alpha * (acc[mi][ni][rg] + bias);
                        }
                    }
                }
            }
            __syncthreads();

            if (w < 2) {
                int sr = tid >> 4, cg = tid & 15;
                int t = m0r + (sl << 5) + sr;
                int h = hbase + (cg >> 3);
                int d0 = (cg & 7) << 4;
                const float* SR = slab + sr * 260 + cg * 16;
                ushort8v h0, h1;
#pragma unroll
                for (int p = 0; p < 4; ++p) {
                    float x = SR[2 * p], y = SR[2 * p + 1];
                    float4 tb = tab[(t << 6) | ((d0 >> 1) + p)];
                    float c = (w == 0) ? tb.x : tb.z;
                    float s = (w == 0) ? tb.y : tb.w;
                    h0[2 * p]     = f2bf(x * c - y * s);
                    h0[2 * p + 1] = f2bf(y * c + x * s);
                }
#pragma unroll
                for (int p = 0; p < 4; ++p) {
                    float x = SR[8 + 2 * p], y = SR[8 + 2 * p + 1];
                    float4 tb = tab[(t << 6) | ((d0 >> 1) + 4 + p)];
                    float c = (w == 0) ? tb.x : tb.z;
                    float s = (w == 0) ? tb.y : tb.w;
                    h1[2 * p]     = f2bf(x * c - y * s);
                    h1[2 * p + 1] = f2bf(y * c + x * s);
                }
                unsigned short* DR = qk + (((size_t)(b_ * HH + h)) << 17) + ((size_t)t << 7) + d0;
                *(ushort8v*)(DR) = h0;
                *(ushort8v*)(DR + 8) = h1;
            } else {
                int vcol = tid >> 1, th = tid & 1;
                int h = hbase + (vcol >> 7), d = vcol & 127;
                ushort8v h0, h1;
#pragma unroll
                for (int p = 0; p < 8; ++p)
                    h0[p] = f2bf(slab[(th * 16 + p) * 260 + vcol]);
#pragma unroll
                for (int p = 0; p < 8; ++p)
                    h1[p] = f2bf(slab[(th * 16 + 8 + p) * 260 + vcol]);
                unsigned short* DR = vt + (((size_t)((b_ * HH + h) * 128 + d)) << 10)
                                     + m0r + (sl << 5) + th * 16;
                *(ushort8v*)(DR) = h0;
                *(ushort8v*)(DR + 8) = h1;
            }
            __syncthreads();
        }
    }
}

// ---------------------------------------------------------------------------
// scores_k: one block per causal 128x128 tile (round-11 single-buffered).
// e = exp(S + rel - 15) written bf16 into ebuf; row partials into psum.
// ---------------------------------------------------------------------------
__global__ __launch_bounds__(256)
void scores_k(const unsigned short* __restrict__ qb, const unsigned short* __restrict__ kb,
              const float* __restrict__ rel, unsigned short* __restrict__ ebuf,
              float* __restrict__ psum) {
    __shared__ alignas(16) char smem[16384];
    unsigned short* lA = (unsigned short*)smem;
    unsigned short* lB = (unsigned short*)(smem + 8192);
    float* slab = (float*)smem;

    const int tid = threadIdx.x;
    const int lane = tid & 63, wave = tid >> 6;
    const int wr = wave >> 1, wc = wave & 1;
    const int fr = lane & 15, fq = lane >> 4;

    const int flat = blockIdx.y * 36 + blockIdx.x;
    const int xcd = flat & 7, rmp = flat >> 3;
    int idx = rmp % 36;
    const int bh = (rmp / 36) * 8 + xcd;

    int tt = (int)((sqrtf(8.f * (float)idx + 1.f) - 1.f) * 0.5f);
    while ((tt + 1) * (tt + 2) / 2 <= idx) ++tt;
    while (tt * (tt + 1) / 2 > idx) --tt;
    const int ss = idx - tt * (tt + 1) / 2;
    const int t0 = tt << 7, s0 = ss << 7;

    const unsigned short* Q = qb + ((size_t)bh << 17);
    const unsigned short* K = kb + ((size_t)bh << 17);

    f32x4 acc[4][4];
#pragma unroll
    for (int i = 0; i < 4; ++i)
#pragma unroll
        for (int j = 0; j < 4; ++j) acc[i][j] = (f32x4){0.f, 0.f, 0.f, 0.f};

    for (int k0 = 0; k0 < 128; k0 += 32) {
#pragma unroll
        for (int i = 0; i < 2; ++i) {
            int c = i * 256 + tid;
            int r = c >> 2, kc = c & 3;
            gload16(Q + (size_t)(t0 + r) * 128 + k0 + kc * 8, &lA[c * 8]);
        }
#pragma unroll
        for (int i = 0; i < 2; ++i) {
            int c = i * 256 + tid;
            int r = c >> 2, kc = c & 3;
            gload16(K + (size_t)(s0 + r) * 128 + k0 + kc * 8, &lB[c * 8]);
        }
        __syncthreads();

        short8 afr[4], bfr[4];
#pragma unroll
        for (int mi = 0; mi < 4; ++mi)
            afr[mi] = *(const short8*)&lA[(wr * 64 + mi * 16 + fr) * 32 + fq * 8];
#pragma unroll
        for (int ni = 0; ni < 4; ++ni)
            bfr[ni] = *(const short8*)&lB[(wc * 64 + ni * 16 + fr) * 32 + fq * 8];
#pragma unroll
        for (int mi = 0; mi < 4; ++mi)
#pragma unroll
            for (int ni = 0; ni < 4; ++ni)
                acc[mi][ni] = __builtin_amdgcn_mfma_f32_16x16x32_bf16(
                    afr[mi], bfr[ni], acc[mi][ni], 0, 0, 0);
        __syncthreads();
    }

    unsigned short* EO = ebuf + ((size_t)bh << 20);
    const float* RLb = rel + ((size_t)bh << 20);
#pragma unroll
    for (int sl = 0; sl < 4; ++sl) {
        if (wr == (sl >> 1)) {
#pragma unroll
            for (int mi2 = 0; mi2 < 2; ++mi2) {
                int mi = ((sl & 1) << 1) + mi2;
#pragma unroll
                for (int ni = 0; ni < 4; ++ni)
#pragma unroll
                    for (int r = 0; r < 4; ++r) {
                        int srow = (mi2 << 4) + (fq << 2) + r;
                        int col = (wc << 6) + (ni << 4) + fr;
                        slab[srow * 128 + (col ^ (((srow >> 2) & 3) << 4))] = acc[mi][ni][r];
                    }
            }
        }
        __syncthreads();
        {
            int srow = tid >> 3;
            int tg = t0 + (sl << 5) + srow;
            const float* RL = RLb + ((size_t)tg << 10) + s0;
            unsigned short* ER = EO + ((size_t)tg << 10) + s0;
            float rsum = 0.f;
#pragma unroll
            for (int c = 0; c < 4; ++c) {
                int col = ((tid & 7) << 2) + (c << 5);
                float4 sv = *(const float4*)&slab[srow * 128 + (col ^ (((srow >> 2) & 3) << 4))];
                float4 rl = *(const float4*)(RL + col);
                float4 e;
                e.x = (s0 + col     <= tg) ? __expf(sv.x + rl.x - 15.f) : 0.f;
                e.y = (s0 + col + 1 <= tg) ? __expf(sv.y + rl.y - 15.f) : 0.f;
                e.z = (s0 + col + 2 <= tg) ? __expf(sv.z + rl.z - 15.f) : 0.f;
                e.w = (s0 + col + 3 <= tg) ? __expf(sv.w + rl.w - 15.f) : 0.f;
                ushort4v h;
                h.x = f2bf(e.x); h.y = f2bf(e.y); h.z = f2bf(e.z); h.w = f2bf(e.w);
                *(ushort4v*)(ER + col) = h;
                rsum += e.x + e.y + e.z + e.w;
            }
            rsum += __shfl_xor(rsum, 1);
            rsum += __shfl_xor(rsum, 2);
            rsum += __shfl_xor(rsum, 4);
            if ((tid & 7) == 0)
                psum[((((size_t)bh << 10) + tg) << 3) + ss] = rsum;
        }
        __syncthreads();
    }
}

// ---------------------------------------------------------------------------
// pv_k: slim PV GEMM only (no P write, no zero-fill). Per (bh, 64-row strip):
// stage e + V^T swizzled (single-buffered, 24.6KB -> 6 blocks/CU), MFMA,
// O * 1/l -> am. P materialization moved to normP_k.
// ---------------------------------------------------------------------------
__global__ __launch_bounds__(256)
void pv_k(const unsigned short* __restrict__ ebuf, const unsigned short* __restrict__ vt,
          const float* __restrict__ psum, unsigned short* __restrict__ am) {
    __shared__ alignas(16) unsigned short lE[64 * 64];
    __shared__ alignas(16) unsigned short lV[128 * 64];
    __shared__ float lInvF[64];

    const int tid = threadIdx.x;
    const int lane = tid & 63, wave = tid >> 6;
    const int wr = wave >> 1, wc = wave & 1;
    const int fr = lane & 15, fq = lane >> 4;
    const int strip = 15 - blockIdx.y;        // heavy first
    const int t0 = strip << 6;
    const int bh = blockIdx.x;
    const int hh = bh & 15, bb = bh >> 4;
    const int n_s = strip + 1;

    const unsigned short* EB = ebuf + ((size_t)bh << 20) + ((size_t)t0 << 10);
    const unsigned short* Vb = vt + ((size_t)bh << 17);

    if (tid < 64) {
        const float* p = psum + ((((size_t)bh << 10) + t0 + tid) << 3);
        const int tt = t0 >> 7;
        float s = 0.f;
#pragma unroll
        for (int j = 0; j < 8; ++j) s += (j <= tt) ? p[j] : 0.f;
        lInvF[tid] = 1.f / s;
    }

    f32x4 acc[2][4];
#pragma unroll
    for (int i = 0; i < 2; ++i)
#pragma unroll
        for (int j = 0; j < 4; ++j) acc[i][j] = (f32x4){0.f, 0.f, 0.f, 0.f};

    for (int j = 0; j < n_s; ++j) {
        int s0 = j << 6;
        __syncthreads();
#pragma unroll
        for (int i = 0; i < 2; ++i) {
            int o = (i * 256 + tid) * 16;
            int r = o >> 7;
            int cb = (o & 127) ^ ((r & 7) << 4);
            gload16(EB + (size_t)r * 1024 + s0 + (cb >> 1), (char*)lE + o);
        }
#pragma unroll
        for (int i = 0; i < 4; ++i) {
            int o = (i * 256 + tid) * 16;
            int r = o >> 7;
            int cb = (o & 127) ^ ((r & 7) << 4);
            gload16(Vb + (size_t)r * 1024 + s0 + (cb >> 1), (char*)lV + o);
        }
        __syncthreads();

#pragma unroll
        for (int ks = 0; ks < 2; ++ks) {
            short8 pf[2], vf[4];
#pragma unroll
            for (int mi = 0; mi < 2; ++mi) {
                int row = wr * 32 + mi * 16 + fr;
                int cb = (ks * 64 + fq * 16) ^ ((row & 7) << 4);
                pf[mi] = *(const short8*)((const char*)lE + row * 128 + cb);
            }
#pragma unroll
            for (int ni = 0; ni < 4; ++ni) {
                int row = wc * 64 + ni * 16 + fr;
                int cb = (ks * 64 + fq * 16) ^ ((row & 7) << 4);
                vf[ni] = *(const short8*)((const char*)lV + row * 128 + cb);
            }
#pragma unroll
            for (int mi = 0; mi < 2; ++mi)
#pragma unroll
                for (int ni = 0; ni < 4; ++ni)
                    acc[mi][ni] = __builtin_amdgcn_mfma_f32_16x16x32_bf16(
                        pf[mi], vf[ni], acc[mi][ni], 0, 0, 0);
        }
    }

    // O epilogue: scale by 1/l, write am (B,L,E) bf16
#pragma unroll
    for (int mi = 0; mi < 2; ++mi)
#pragma unroll
        for (int ni = 0; ni < 4; ++ni)
#pragma unroll
            for (int r = 0; r < 4; ++r) {
                int tl = wr * 32 + mi * 16 + fq * 4 + r;
                int d = wc * 64 + ni * 16 + fr;
                float o = acc[mi][ni][r] * lInvF[tl];
                am[(((size_t)(bb * 1024 + t0 + tl)) << 11) + hh * 128 + d] = f2bf(o);
            }
}

// ---------------------------------------------------------------------------
// normP_k: pure streaming. One thread = 16 cols of one P row.
// Reads ebuf bf16 (L3-hot) * inv(psum), writes fp32 P incl. upper-zero fill.
// Block = 4 rows (256 threads); grid = 65536/4 = 16384 blocks.
// ---------------------------------------------------------------------------
__global__ __launch_bounds__(256)
void normP_k(const unsigned short* __restrict__ ebuf, const float* __restrict__ psum,
             float* __restrict__ attnP) {
    const int gid = blockIdx.x * 4 + (threadIdx.x >> 6);   // row id (bh<<10)|t
    const int lane = threadIdx.x & 63;
    const int bh = gid >> 10, t = gid & 1023;
    const int hh = bh & 15, bb = bh >> 4;
    const int tt = t >> 7;
    const int kend = (tt + 1) << 7;

    const float* p = psum + ((size_t)gid << 3);
    float s = 0.f;
#pragma unroll
    for (int j = 0; j < 8; ++j) s += (j <= tt) ? p[j] : 0.f;
    const float inv = 1.f / s;

    const unsigned short* ER = ebuf + ((size_t)gid << 10);
    float* PR = attnP + (((size_t)(hh * BB + bb)) << 20) + ((size_t)t << 10);
    const int col = lane << 4;

    if (col < kend) {
        ushort8v e0 = *(const ushort8v*)(ER + col);
        ushort8v e1 = *(const ushort8v*)(ER + col + 8);
        float4 o0, o1, o2, o3;
        o0.x = bf2f(e0[0]) * inv; o0.y = bf2f(e0[1]) * inv;
        o0.z = bf2f(e0[2]) * inv; o0.w = bf2f(e0[3]) * inv;
        o1.x = bf2f(e0[4]) * inv; o1.y = bf2f(e0[5]) * inv;
        o1.z = bf2f(e0[6]) * inv; o1.w = bf2f(e0[7]) * inv;
        o2.x = bf2f(e1[0]) * inv; o2.y = bf2f(e1[1]) * inv;
        o2.z = bf2f(e1[2]) * inv; o2.w = bf2f(e1[3]) * inv;
        o3.x = bf2f(e1[4]) * inv; o3.y = bf2f(e1[5]) * inv;
        o3.z = bf2f(e1[6]) * inv; o3.w = bf2f(e1[7]) * inv;
        *(float4*)(PR + col)      = o0;
        *(float4*)(PR + col + 4)  = o1;
        *(float4*)(PR + col + 8)  = o2;
        *(float4*)(PR + col + 12) = o3;
    } else {
        float4 z = make_float4(0.f, 0.f, 0.f, 0.f);
        *(float4*)(PR + col)      = z;
        *(float4*)(PR + col + 4)  = z;
        *(float4*)(PR + col + 8)  = z;
        *(float4*)(PR + col + 12) = z;
    }
}

// ---------------------------------------------------------------------------
extern "C" void kernel_launch(void* const* d_in, const int* in_sizes, int n_in,
                              void* d_out, int out_size, void* d_ws, size_t ws_size,
                              hipStream_t stream) {
    const float* query = (const float*)d_in[0];
    const float* Wq    = (const float*)d_in[1];
    const float* bq    = (const float*)d_in[2];
    const float* Wk    = (const float*)d_in[3];
    const float* bk    = (const float*)d_in[4];
    const float* Wv    = (const float*)d_in[5];
    const float* bv    = (const float*)d_in[6];
    const float* Wo    = (const float*)d_in[7];
    const float* bo    = (const float*)d_in[8];
    const float* rel   = (const float*)d_in[10];

    float* out    = (float*)d_out;              // (B, L, E)
    float* attn_w = out + OUT0_ELEMS;           // (H, B, L, L)

    char* w = (char*)d_ws;
    unsigned short* Xbf   = (unsigned short*)(w);               // 16MB
    unsigned short* Wqkvb = (unsigned short*)(w + (16 << 20));  // 24MB
    unsigned short* Wob   = (unsigned short*)(w + (40 << 20));  // 8MB
    unsigned short* qb    = (unsigned short*)(w + (48 << 20));  // 16MB (BH,L,DH)
    unsigned short* kb    = (unsigned short*)(w + (64 << 20));  // 16MB
    unsigned short* vt    = (unsigned short*)(w + (80 << 20));  // 16MB (BH,DH,L)
    unsigned short* am    = (unsigned short*)(w + (96 << 20));  // 16MB (B,L,E)
    float4* tab           = (float4*)(w + (112 << 20));         // 1MB
    float* psum           = (float*)(w + (113u << 20));         // 2MB
    unsigned short* ebuf  = (unsigned short*)(w + (128u << 20)); // 128MB

    const float scaling = 0.08838834764831845f; // DH^-0.5

    xpos_table_k<<<LL, 64, 0, stream>>>(tab);

    cvt_all_k<<<12288, 256, 0, stream>>>(query, Wq, Wk, Wv, Wo, Xbf, Wqkvb, Wob);

    dim3 gqkv(24, 32);                           // 128x256 tiles, 768 blocks
    mm8_k<0><<<gqkv, 512, 0, stream>>>(Xbf, Wqkvb, bq, bk, bv, qb, kb, vt, tab,
                                       nullptr, scaling);

    dim3 gsc(36, NBH);
    scores_k<<<gsc, 256, 0, stream>>>(qb, kb, rel, ebuf, psum);

    dim3 gpv(NBH, 16);
    pv_k<<<gpv, 256, 0, stream>>>(ebuf, vt, psum, am);

    normP_k<<<16384, 256, 0, stream>>>(ebuf, psum, attn_w);

    dim3 gout(8, 32);                            // 128x256 tiles, 256 blocks
    mm8_k<1><<<gout, 512, 0, stream>>>(am, Wob, bo, nullptr, nullptr, nullptr,
                                       nullptr, nullptr, tab, out, 1.0f);
}

// Round 14
// 413.336 us; speedup vs baseline: 1.0566x; 1.0168x over previous
//
#include <hip/hip_runtime.h>
#include <math.h>

// (B, L, E, H) = (4, 1024, 2048, 16), DH = 128
#define BB 4
#define LL 1024
#define EE 2048
#define HH 16
#define DHD 128
#define NTOK 4096
#define NBH 64
#define OUT0_ELEMS 8388608     // B*L*E

typedef __attribute__((ext_vector_type(8))) short short8;
typedef __attribute__((ext_vector_type(4))) float f32x4;
typedef __attribute__((ext_vector_type(4))) unsigned short ushort4v;
typedef __attribute__((ext_vector_type(8))) unsigned short ushort8v;

__device__ __forceinline__ unsigned short f2bf(float x) {
    union { float f; unsigned int u; } v; v.f = x;
    unsigned int r = v.u + 0x7FFFu + ((v.u >> 16) & 1u);   // RNE
    return (unsigned short)(r >> 16);
}
__device__ __forceinline__ float bf2f(unsigned short h) {
    union { unsigned int u; float f; } v; v.u = ((unsigned int)h) << 16;
    return v.f;
}

__device__ __forceinline__ void gload16(const void* g, void* l) {
    __builtin_amdgcn_global_load_lds((const __attribute__((address_space(1))) void*)g,
                                     (__attribute__((address_space(3))) void*)l,
                                     16, 0, 0);
}

// ---------------------------------------------------------------------------
// Region-dispatched: fp32->bf16 convert of X + 4 weights (blocks 0..12287)
// and xPos table (blocks 12288..12543).
// ---------------------------------------------------------------------------
__global__ __launch_bounds__(256)
void cvt_all_k(const float* __restrict__ X, const float* __restrict__ Wq,
               const float* __restrict__ Wk, const float* __restrict__ Wv,
               const float* __restrict__ Wo, unsigned short* __restrict__ Xbf,
               unsigned short* __restrict__ Wqkvb, unsigned short* __restrict__ Wob,
               float4* __restrict__ tab) {
    const int bid = blockIdx.x;
    if (bid >= 12288) {
        int g = (bid - 12288) * 256 + threadIdx.x;   // 0..65535
        int t = g >> 6, j = g & 63;
        float pos = (float)(t - 512);
        float base = (2.0f * (float)j + 51.2f) * (1.0f / 179.2f);
        float sc = powf(base, pos * (1.0f / 512.0f));
        float inv_freq = powf(10000.0f, -(float)j * (1.0f / 64.0f));
        float ang = (float)t * inv_freq;
        float s = sinf(ang);
        float c = cosf(ang);
        tab[(t << 6) | j] = make_float4(c * sc, s * sc, c / sc, s / sc);
        return;
    }
    size_t g = (size_t)(bid * 256 + threadIdx.x) * 8;
    const float* src;
    unsigned short* dst;
    if (g < 8388608u) {
        src = X + g; dst = Xbf + g;
    } else {
        size_t rr = g - 8388608u;
        int wi = (int)(rr >> 22);
        size_t o = rr & 4194303u;
        src = (wi == 0 ? Wq : wi == 1 ? Wk : wi == 2 ? Wv : Wo) + o;
        dst = (wi < 3 ? Wqkvb + ((size_t)wi << 22) : Wob) + o;
    }
    float4 a = *(const float4*)(src);
    float4 b = *(const float4*)(src + 4);
    ushort4v u, w;
    u.x = f2bf(a.x); u.y = f2bf(a.y); u.z = f2bf(a.z); u.w = f2bf(a.w);
    w.x = f2bf(b.x); w.y = f2bf(b.y); w.z = f2bf(b.z); w.w = f2bf(b.w);
    *(ushort4v*)(dst) = u;
    *(ushort4v*)(dst + 4) = w;
}

// ---------------------------------------------------------------------------
// 128x256 8-phase bf16 GEMM (T2+T3+T4+T5), K=2048, BK=64, 8 waves.
// (unchanged from round 11)
// ---------------------------------------------------------------------------
template <int MODE>
__global__ __launch_bounds__(512, 2)
void mm8_k(const unsigned short* __restrict__ Abf, const unsigned short* __restrict__ Bw,
           const float* __restrict__ bq, const float* __restrict__ bk,
           const float* __restrict__ bv, unsigned short* __restrict__ qb,
           unsigned short* __restrict__ kb, unsigned short* __restrict__ vt,
           const float4* __restrict__ tab, float* __restrict__ Cout,
           float scaling) {
    __shared__ alignas(16) char smem[98304];

    const int tid = threadIdx.x;
    const int lane = tid & 63;
    const int wid = tid >> 6;
    const int wr = wid >> 2;
    const int wcn = wid & 3;
    const int fr = lane & 15, fq = lane >> 4;

    const int m0 = blockIdx.y * 128, n0 = blockIdx.x * 256;

    auto stageA = [&](int T) {
        char* dst = smem + ((T & 1) << 14);
        const unsigned short* src = Abf + (size_t)m0 * 2048 + T * 64;
#pragma unroll
        for (int j = 0; j < 2; ++j) {
            int o = (j * 512 + tid) * 16;
            int r = o >> 7;
            int cs = ((o & 127) >> 4) ^ (r & 7);
            gload16(src + (size_t)r * 2048 + cs * 8, dst + o);
        }
    };
    auto stageB = [&](int T, int half) {
        char* dst = smem + 32768 + ((T & 1) << 15) + (half << 14);
        const unsigned short* src = Bw + (size_t)(n0 + half * 128) * 2048 + T * 64;
#pragma unroll
        for (int j = 0; j < 2; ++j) {
            int o = (j * 512 + tid) * 16;
            int r = o >> 7;
            int cs = ((o & 127) >> 4) ^ (r & 7);
            gload16(src + (size_t)r * 2048 + cs * 8, dst + o);
        }
    };
    auto rdA = [&](int buf, int mi, int ks) -> short8 {
        int rl = (wr << 6) + mi * 16 + fr;
        const char* base = smem + (buf << 14);
        return *(const short8*)(base + rl * 128 + ((ks * 4 + fq) ^ (rl & 7)) * 16);
    };
    auto rdB = [&](int buf, int ni, int ks) -> short8 {
        int rb = wcn * 64 + ni * 16 + fr;
        const char* base = smem + 32768 + (buf << 15) + ((rb >> 7) << 14);
        int rh = rb & 127;
        return *(const short8*)(base + rh * 128 + ((ks * 4 + fq) ^ (rh & 7)) * 16);
    };

    f32x4 acc[4][4];
#pragma unroll
    for (int i = 0; i < 4; ++i)
#pragma unroll
        for (int j = 0; j < 4; ++j) acc[i][j] = (f32x4){0.f, 0.f, 0.f, 0.f};

    stageA(0); stageB(0, 0); stageB(0, 1); stageB(1, 0); stageB(1, 1);

    for (int T = 0; T < 32; ++T) {
        const int buf = T & 1;
        if (T < 31) asm volatile("s_waitcnt vmcnt(4)" ::: "memory");
        else        asm volatile("s_waitcnt vmcnt(0)" ::: "memory");
        __builtin_amdgcn_s_barrier();

        short8 a0[2][2], a1[2][2], b0[2][2], b1[2][2];

#pragma unroll
        for (int mi = 0; mi < 2; ++mi) { a0[mi][0] = rdA(buf, mi, 0); a0[mi][1] = rdA(buf, mi, 1); }
#pragma unroll
        for (int ni = 0; ni < 2; ++ni) { b0[ni][0] = rdB(buf, ni, 0); b0[ni][1] = rdB(buf, ni, 1); }
        if (T < 31) stageA(T + 1);
        __builtin_amdgcn_s_barrier();
        __builtin_amdgcn_s_setprio(1);
#pragma unroll
        for (int mi = 0; mi < 2; ++mi)
#pragma unroll
            for (int ni = 0; ni < 2; ++ni) {
                acc[mi][ni] = __builtin_amdgcn_mfma_f32_16x16x32_bf16(a0[mi][0], b0[ni][0], acc[mi][ni], 0, 0, 0);
                acc[mi][ni] = __builtin_amdgcn_mfma_f32_16x16x32_bf16(a0[mi][1], b0[ni][1], acc[mi][ni], 0, 0, 0);
            }
        __builtin_amdgcn_s_setprio(0);
        __builtin_amdgcn_s_barrier();

#pragma unroll
        for (int ni = 0; ni < 2; ++ni) { b1[ni][0] = rdB(buf, ni + 2, 0); b1[ni][1] = rdB(buf, ni + 2, 1); }
        __builtin_amdgcn_s_barrier();
        __builtin_amdgcn_s_setprio(1);
#pragma unroll
        for (int mi = 0; mi < 2; ++mi)
#pragma unroll
            for (int ni = 0; ni < 2; ++ni) {
                acc[mi][ni + 2] = __builtin_amdgcn_mfma_f32_16x16x32_bf16(a0[mi][0], b1[ni][0], acc[mi][ni + 2], 0, 0, 0);
                acc[mi][ni + 2] = __builtin_amdgcn_mfma_f32_16x16x32_bf16(a0[mi][1], b1[ni][1], acc[mi][ni + 2], 0, 0, 0);
            }
        __builtin_amdgcn_s_setprio(0);
        __builtin_amdgcn_s_barrier();

#pragma unroll
        for (int mi = 0; mi < 2; ++mi) { a1[mi][0] = rdA(buf, mi + 2, 0); a1[mi][1] = rdA(buf, mi + 2, 1); }
        if (T < 30) stageB(T + 2, 0);
        __builtin_amdgcn_s_barrier();
        __builtin_amdgcn_s_setprio(1);
#pragma unroll
        for (int mi = 0; mi < 2; ++mi)
#pragma unroll
            for (int ni = 0; ni < 2; ++ni) {
                acc[mi + 2][ni] = __builtin_amdgcn_mfma_f32_16x16x32_bf16(a1[mi][0], b0[ni][0], acc[mi + 2][ni], 0, 0, 0);
                acc[mi + 2][ni] = __builtin_amdgcn_mfma_f32_16x16x32_bf16(a1[mi][1], b0[ni][1], acc[mi + 2][ni], 0, 0, 0);
            }
        __builtin_amdgcn_s_setprio(0);
        __builtin_amdgcn_s_barrier();

        if (T < 30) stageB(T + 2, 1);
        __builtin_amdgcn_s_barrier();
        __builtin_amdgcn_s_setprio(1);
#pragma unroll
        for (int mi = 0; mi < 2; ++mi)
#pragma unroll
            for (int ni = 0; ni < 2; ++ni) {
                acc[mi + 2][ni + 2] = __builtin_amdgcn_mfma_f32_16x16x32_bf16(a1[mi][0], b1[ni][0], acc[mi + 2][ni + 2], 0, 0, 0);
                acc[mi + 2][ni + 2] = __builtin_amdgcn_mfma_f32_16x16x32_bf16(a1[mi][1], b1[ni][1], acc[mi + 2][ni + 2], 0, 0, 0);
            }
        __builtin_amdgcn_s_setprio(0);
        __builtin_amdgcn_s_barrier();
    }

    if constexpr (MODE == 1) {
        const float* bias = bq;
#pragma unroll
        for (int mi = 0; mi < 4; ++mi)
#pragma unroll
            for (int ni = 0; ni < 4; ++ni)
#pragma unroll
                for (int rg = 0; rg < 4; ++rg) {
                    int m = m0 + wr * 64 + mi * 16 + fq * 4 + rg;
                    int n = n0 + wcn * 64 + ni * 16 + fr;
                    Cout[(size_t)m * EE + n] = acc[mi][ni][rg] + bias[n];
                }
        return;
    } else {
        const int w = n0 >> 11;
        const float* bsel = (w == 0) ? bq : (w == 1) ? bk : bv;
        const float alpha = (w == 0) ? scaling : 1.0f;
        const int hbase = (n0 & 2047) >> 7;
        const int b_ = m0 >> 10;
        const int m0r = m0 & 1023;
        float* slab = (float*)smem;

        unsigned short* qk = (w == 0) ? qb : kb;
        __syncthreads();
#pragma unroll
        for (int sl = 0; sl < 4; ++sl) {
            if (wr == (sl >> 1)) {
#pragma unroll
                for (int mi2 = 0; mi2 < 2; ++mi2) {
                    int mi = ((sl & 1) << 1) + mi2;
#pragma unroll
                    for (int ni = 0; ni < 4; ++ni) {
                        int scol = wcn * 64 + ni * 16 + fr;
                        float bias = bsel[(n0 & 2047) + scol];
#pragma unroll
                        for (int rg = 0; rg < 4; ++rg) {
                            int srow = (mi2 << 4) + fq * 4 + rg;
                            slab[srow * 260 + scol] = alpha * (acc[mi][ni][rg] + bias);
                        }
                    }
                }
            }
            __syncthreads();

            if (w < 2) {
                int sr = tid >> 4, cg = tid & 15;
                int t = m0r + (sl << 5) + sr;
                int h = hbase + (cg >> 3);
                int d0 = (cg & 7) << 4;
                const float* SR = slab + sr * 260 + cg * 16;
                ushort8v h0, h1;
#pragma unroll
                for (int p = 0; p < 4; ++p) {
                    float x = SR[2 * p], y = SR[2 * p + 1];
                    float4 tb = tab[(t << 6) | ((d0 >> 1) + p)];
                    float c = (w == 0) ? tb.x : tb.z;
                    float s = (w == 0) ? tb.y : tb.w;
                    h0[2 * p]     = f2bf(x * c - y * s);
                    h0[2 * p + 1] = f2bf(y * c + x * s);
                }
#pragma unroll
                for (int p = 0; p < 4; ++p) {
                    float x = SR[8 + 2 * p], y = SR[8 + 2 * p + 1];
                    float4 tb = tab[(t << 6) | ((d0 >> 1) + 4 + p)];
                    float c = (w == 0) ? tb.x : tb.z;
                    float s = (w == 0) ? tb.y : tb.w;
                    h1[2 * p]     = f2bf(x * c - y * s);
                    h1[2 * p + 1] = f2bf(y * c + x * s);
                }
                unsigned short* DR = qk + (((size_t)(b_ * HH + h)) << 17) + ((size_t)t << 7) + d0;
                *(ushort8v*)(DR) = h0;
                *(ushort8v*)(DR + 8) = h1;
            } else {
                int vcol = tid >> 1, th = tid & 1;
                int h = hbase + (vcol >> 7), d = vcol & 127;
                ushort8v h0, h1;
#pragma unroll
                for (int p = 0; p < 8; ++p)
                    h0[p] = f2bf(slab[(th * 16 + p) * 260 + vcol]);
#pragma unroll
                for (int p = 0; p < 8; ++p)
                    h1[p] = f2bf(slab[(th * 16 + 8 + p) * 260 + vcol]);
                unsigned short* DR = vt + (((size_t)((b_ * HH + h) * 128 + d)) << 10)
                                     + m0r + (sl << 5) + th * 16;
                *(ushort8v*)(DR) = h0;
                *(ushort8v*)(DR + 8) = h1;
            }
            __syncthreads();
        }
    }
}

// ---------------------------------------------------------------------------
// scores_k: one block per causal 128x128 tile (single-buffered).
// e = exp(S + rel - 15) written bf16 into ebuf; row partials into psum.
// ---------------------------------------------------------------------------
__global__ __launch_bounds__(256)
void scores_k(const unsigned short* __restrict__ qb, const unsigned short* __restrict__ kb,
              const float* __restrict__ rel, unsigned short* __restrict__ ebuf,
              float* __restrict__ psum) {
    __shared__ alignas(16) char smem[16384];
    unsigned short* lA = (unsigned short*)smem;
    unsigned short* lB = (unsigned short*)(smem + 8192);
    float* slab = (float*)smem;

    const int tid = threadIdx.x;
    const int lane = tid & 63, wave = tid >> 6;
    const int wr = wave >> 1, wc = wave & 1;
    const int fr = lane & 15, fq = lane >> 4;

    const int flat = blockIdx.y * 36 + blockIdx.x;
    const int xcd = flat & 7, rmp = flat >> 3;
    int idx = rmp % 36;
    const int bh = (rmp / 36) * 8 + xcd;

    int tt = (int)((sqrtf(8.f * (float)idx + 1.f) - 1.f) * 0.5f);
    while ((tt + 1) * (tt + 2) / 2 <= idx) ++tt;
    while (tt * (tt + 1) / 2 > idx) --tt;
    const int ss = idx - tt * (tt + 1) / 2;
    const int t0 = tt << 7, s0 = ss << 7;

    const unsigned short* Q = qb + ((size_t)bh << 17);
    const unsigned short* K = kb + ((size_t)bh << 17);

    f32x4 acc[4][4];
#pragma unroll
    for (int i = 0; i < 4; ++i)
#pragma unroll
        for (int j = 0; j < 4; ++j) acc[i][j] = (f32x4){0.f, 0.f, 0.f, 0.f};

    for (int k0 = 0; k0 < 128; k0 += 32) {
#pragma unroll
        for (int i = 0; i < 2; ++i) {
            int c = i * 256 + tid;
            int r = c >> 2, kc = c & 3;
            gload16(Q + (size_t)(t0 + r) * 128 + k0 + kc * 8, &lA[c * 8]);
        }
#pragma unroll
        for (int i = 0; i < 2; ++i) {
            int c = i * 256 + tid;
            int r = c >> 2, kc = c & 3;
            gload16(K + (size_t)(s0 + r) * 128 + k0 + kc * 8, &lB[c * 8]);
        }
        __syncthreads();

        short8 afr[4], bfr[4];
#pragma unroll
        for (int mi = 0; mi < 4; ++mi)
            afr[mi] = *(const short8*)&lA[(wr * 64 + mi * 16 + fr) * 32 + fq * 8];
#pragma unroll
        for (int ni = 0; ni < 4; ++ni)
            bfr[ni] = *(const short8*)&lB[(wc * 64 + ni * 16 + fr) * 32 + fq * 8];
#pragma unroll
        for (int mi = 0; mi < 4; ++mi)
#pragma unroll
            for (int ni = 0; ni < 4; ++ni)
                acc[mi][ni] = __builtin_amdgcn_mfma_f32_16x16x32_bf16(
                    afr[mi], bfr[ni], acc[mi][ni], 0, 0, 0);
        __syncthreads();
    }

    unsigned short* EO = ebuf + ((size_t)bh << 20);
    const float* RLb = rel + ((size_t)bh << 20);
#pragma unroll
    for (int sl = 0; sl < 4; ++sl) {
        if (wr == (sl >> 1)) {
#pragma unroll
            for (int mi2 = 0; mi2 < 2; ++mi2) {
                int mi = ((sl & 1) << 1) + mi2;
#pragma unroll
                for (int ni = 0; ni < 4; ++ni)
#pragma unroll
                    for (int r = 0; r < 4; ++r) {
                        int srow = (mi2 << 4) + (fq << 2) + r;
                        int col = (wc << 6) + (ni << 4) + fr;
                        slab[srow * 128 + (col ^ (((srow >> 2) & 3) << 4))] = acc[mi][ni][r];
                    }
            }
        }
        __syncthreads();
        {
            int srow = tid >> 3;
            int tg = t0 + (sl << 5) + srow;
            const float* RL = RLb + ((size_t)tg << 10) + s0;
            unsigned short* ER = EO + ((size_t)tg << 10) + s0;
            float rsum = 0.f;
#pragma unroll
            for (int c = 0; c < 4; ++c) {
                int col = ((tid & 7) << 2) + (c << 5);
                float4 sv = *(const float4*)&slab[srow * 128 + (col ^ (((srow >> 2) & 3) << 4))];
                float4 rl = *(const float4*)(RL + col);
                float4 e;
                e.x = (s0 + col     <= tg) ? __expf(sv.x + rl.x - 15.f) : 0.f;
                e.y = (s0 + col + 1 <= tg) ? __expf(sv.y + rl.y - 15.f) : 0.f;
                e.z = (s0 + col + 2 <= tg) ? __expf(sv.z + rl.z - 15.f) : 0.f;
                e.w = (s0 + col + 3 <= tg) ? __expf(sv.w + rl.w - 15.f) : 0.f;
                ushort4v h;
                h.x = f2bf(e.x); h.y = f2bf(e.y); h.z = f2bf(e.z); h.w = f2bf(e.w);
                *(ushort4v*)(ER + col) = h;
                rsum += e.x + e.y + e.z + e.w;
            }
            rsum += __shfl_xor(rsum, 1);
            rsum += __shfl_xor(rsum, 2);
            rsum += __shfl_xor(rsum, 4);
            if ((tid & 7) == 0)
                psum[((((size_t)bh << 10) + tg) << 3) + ss] = rsum;
        }
        __syncthreads();
    }
}

// ---------------------------------------------------------------------------
// pvnp_k: region-dispatched fusion of the PV GEMM (blocks 0..1023) and the
// streaming P-normalize/write (blocks 1024..17407). Both consume ebuf/psum
// (L3-hot), write disjoint outputs -> MFMA-bound and BW-bound blocks share
// the machine instead of serializing as two launches.
// ---------------------------------------------------------------------------
__global__ __launch_bounds__(256)
void pvnp_k(const unsigned short* __restrict__ ebuf, const unsigned short* __restrict__ vt,
            const float* __restrict__ psum, float* __restrict__ attnP,
            unsigned short* __restrict__ am) {
    __shared__ alignas(16) unsigned short lE[64 * 64];
    __shared__ alignas(16) unsigned short lV[128 * 64];
    __shared__ float lInvF[64];

    const int bid = blockIdx.x;
    const int tid = threadIdx.x;

    if (bid >= 1024) {
        // ---------------- normP path: pure streaming ----------------
        const int gid = (bid - 1024) * 4 + (tid >> 6);   // row id (bh<<10)|t
        const int lane = tid & 63;
        const int bh = gid >> 10, t = gid & 1023;
        const int hh = bh & 15, bb = bh >> 4;
        const int tt = t >> 7;
        const int kend = (tt + 1) << 7;

        const float* p = psum + ((size_t)gid << 3);
        float s = 0.f;
#pragma unroll
        for (int j = 0; j < 8; ++j) s += (j <= tt) ? p[j] : 0.f;
        const float inv = 1.f / s;

        const unsigned short* ER = ebuf + ((size_t)gid << 10);
        float* PR = attnP + (((size_t)(hh * BB + bb)) << 20) + ((size_t)t << 10);
        const int col = lane << 4;

        if (col < kend) {
            ushort8v e0 = *(const ushort8v*)(ER + col);
            ushort8v e1 = *(const ushort8v*)(ER + col + 8);
            float4 o0, o1, o2, o3;
            o0.x = bf2f(e0[0]) * inv; o0.y = bf2f(e0[1]) * inv;
            o0.z = bf2f(e0[2]) * inv; o0.w = bf2f(e0[3]) * inv;
            o1.x = bf2f(e0[4]) * inv; o1.y = bf2f(e0[5]) * inv;
            o1.z = bf2f(e0[6]) * inv; o1.w = bf2f(e0[7]) * inv;
            o2.x = bf2f(e1[0]) * inv; o2.y = bf2f(e1[1]) * inv;
            o2.z = bf2f(e1[2]) * inv; o2.w = bf2f(e1[3]) * inv;
            o3.x = bf2f(e1[4]) * inv; o3.y = bf2f(e1[5]) * inv;
            o3.z = bf2f(e1[6]) * inv; o3.w = bf2f(e1[7]) * inv;
            *(float4*)(PR + col)      = o0;
            *(float4*)(PR + col + 4)  = o1;
            *(float4*)(PR + col + 8)  = o2;
            *(float4*)(PR + col + 12) = o3;
        } else {
            float4 z = make_float4(0.f, 0.f, 0.f, 0.f);
            *(float4*)(PR + col)      = z;
            *(float4*)(PR + col + 4)  = z;
            *(float4*)(PR + col + 8)  = z;
            *(float4*)(PR + col + 12) = z;
        }
        return;
    }

    // ---------------- pv path: slim PV GEMM ----------------
    const int lane = tid & 63, wave = tid >> 6;
    const int wr = wave >> 1, wc = wave & 1;
    const int fr = lane & 15, fq = lane >> 4;
    const int strip = 15 - (bid >> 6);        // heavy strips first
    const int t0 = strip << 6;
    const int bh = bid & 63;
    const int hh = bh & 15, bb = bh >> 4;
    const int n_s = strip + 1;

    const unsigned short* EB = ebuf + ((size_t)bh << 20) + ((size_t)t0 << 10);
    const unsigned short* Vb = vt + ((size_t)bh << 17);

    if (tid < 64) {
        const float* p = psum + ((((size_t)bh << 10) + t0 + tid) << 3);
        const int tt = t0 >> 7;
        float s = 0.f;
#pragma unroll
        for (int j = 0; j < 8; ++j) s += (j <= tt) ? p[j] : 0.f;
        lInvF[tid] = 1.f / s;
    }

    f32x4 acc[2][4];
#pragma unroll
    for (int i = 0; i < 2; ++i)
#pragma unroll
        for (int j = 0; j < 4; ++j) acc[i][j] = (f32x4){0.f, 0.f, 0.f, 0.f};

    for (int j = 0; j < n_s; ++j) {
        int s0 = j << 6;
        __syncthreads();
#pragma unroll
        for (int i = 0; i < 2; ++i) {
            int o = (i * 256 + tid) * 16;
            int r = o >> 7;
            int cb = (o & 127) ^ ((r & 7) << 4);
            gload16(EB + (size_t)r * 1024 + s0 + (cb >> 1), (char*)lE + o);
        }
#pragma unroll
        for (int i = 0; i < 4; ++i) {
            int o = (i * 256 + tid) * 16;
            int r = o >> 7;
            int cb = (o & 127) ^ ((r & 7) << 4);
            gload16(Vb + (size_t)r * 1024 + s0 + (cb >> 1), (char*)lV + o);
        }
        __syncthreads();

#pragma unroll
        for (int ks = 0; ks < 2; ++ks) {
            short8 pf[2], vf[4];
#pragma unroll
            for (int mi = 0; mi < 2; ++mi) {
                int row = wr * 32 + mi * 16 + fr;
                int cb = (ks * 64 + fq * 16) ^ ((row & 7) << 4);
                pf[mi] = *(const short8*)((const char*)lE + row * 128 + cb);
            }
#pragma unroll
            for (int ni = 0; ni < 4; ++ni) {
                int row = wc * 64 + ni * 16 + fr;
                int cb = (ks * 64 + fq * 16) ^ ((row & 7) << 4);
                vf[ni] = *(const short8*)((const char*)lV + row * 128 + cb);
            }
#pragma unroll
            for (int mi = 0; mi < 2; ++mi)
#pragma unroll
                for (int ni = 0; ni < 4; ++ni)
                    acc[mi][ni] = __builtin_amdgcn_mfma_f32_16x16x32_bf16(
                        pf[mi], vf[ni], acc[mi][ni], 0, 0, 0);
        }
    }

    // O epilogue: scale by 1/l, write am (B,L,E) bf16
#pragma unroll
    for (int mi = 0; mi < 2; ++mi)
#pragma unroll
        for (int ni = 0; ni < 4; ++ni)
#pragma unroll
            for (int r = 0; r < 4; ++r) {
                int tl = wr * 32 + mi * 16 + fq * 4 + r;
                int d = wc * 64 + ni * 16 + fr;
                float o = acc[mi][ni][r] * lInvF[tl];
                am[(((size_t)(bb * 1024 + t0 + tl)) << 11) + hh * 128 + d] = f2bf(o);
            }
}

// ---------------------------------------------------------------------------
extern "C" void kernel_launch(void* const* d_in, const int* in_sizes, int n_in,
                              void* d_out, int out_size, void* d_ws, size_t ws_size,
                              hipStream_t stream) {
    const float* query = (const float*)d_in[0];
    const float* Wq    = (const float*)d_in[1];
    const float* bq    = (const float*)d_in[2];
    const float* Wk    = (const float*)d_in[3];
    const float* bk    = (const float*)d_in[4];
    const float* Wv    = (const float*)d_in[5];
    const float* bv    = (const float*)d_in[6];
    const float* Wo    = (const float*)d_in[7];
    const float* bo    = (const float*)d_in[8];
    const float* rel   = (const float*)d_in[10];

    float* out    = (float*)d_out;              // (B, L, E)
    float* attn_w = out + OUT0_ELEMS;           // (H, B, L, L)

    char* w = (char*)d_ws;
    unsigned short* Xbf   = (unsigned short*)(w);               // 16MB
    unsigned short* Wqkvb = (unsigned short*)(w + (16 << 20));  // 24MB
    unsigned short* Wob   = (unsigned short*)(w + (40 << 20));  // 8MB
    unsigned short* qb    = (unsigned short*)(w + (48 << 20));  // 16MB (BH,L,DH)
    unsigned short* kb    = (unsigned short*)(w + (64 << 20));  // 16MB
    unsigned short* vt    = (unsigned short*)(w + (80 << 20));  // 16MB (BH,DH,L)
    unsigned short* am    = (unsigned short*)(w + (96 << 20));  // 16MB (B,L,E)
    float4* tab           = (float4*)(w + (112 << 20));         // 1MB
    float* psum           = (float*)(w + (113u << 20));         // 2MB
    unsigned short* ebuf  = (unsigned short*)(w + (128u << 20)); // 128MB

    const float scaling = 0.08838834764831845f; // DH^-0.5

    cvt_all_k<<<12544, 256, 0, stream>>>(query, Wq, Wk, Wv, Wo, Xbf, Wqkvb, Wob, tab);

    dim3 gqkv(24, 32);                           // 128x256 tiles, 768 blocks
    mm8_k<0><<<gqkv, 512, 0, stream>>>(Xbf, Wqkvb, bq, bk, bv, qb, kb, vt, tab,
                                       nullptr, scaling);

    dim3 gsc(36, NBH);
    scores_k<<<gsc, 256, 0, stream>>>(qb, kb, rel, ebuf, psum);

    pvnp_k<<<17408, 256, 0, stream>>>(ebuf, vt, psum, attn_w, am);

    dim3 gout(8, 32);                            // 128x256 tiles, 256 blocks
    mm8_k<1><<<gout, 512, 0, stream>>>(am, Wob, bo, nullptr, nullptr, nullptr,
                                       nullptr, nullptr, tab, out, 1.0f);
}